// Round 5
// baseline (348.673 us; speedup 1.0000x reference)
//
#include <hip/hip_runtime.h>
#include <math.h>

#define N_NODES 50000
#define N_EDGES 800000
#define G_GRAPHS 64
#define BSTRIDE 64    // epk bucket stride per node (max degree; Poisson(16) tail ~1e-13)
#define CPAD 16       // cnt padded: one counter per 64B line
#define SENPK (N_NODES * 40)   // sentinel payload: byte offset of zero h row, attr=0

#define WAVE_SYNC() asm volatile("s_waitcnt lgkmcnt(0)" ::: "memory")
#define RFL(v) __builtin_amdgcn_readfirstlane(v)
#define RLF(v, k) __int_as_float(__builtin_amdgcn_readlane(__float_as_int(v), (k)))

// ---- zero the used cnt slots (replaces hipMemsetAsync: graph-capture-safe) ----
__global__ void k_zero(int* __restrict__ cnt) {
  int n = blockIdx.x * 256 + threadIdx.x;
  if (n < N_NODES) cnt[n * CPAD] = 0;
}

// ---- fused front: edge scatter (1 edge/thread, cnt pre-zeroed by k_zero) +
// ---- mlp1 h compute + zeroing + enc/encm setup (block 0). u table is GONE:
// ---- conv computes the src-dot on the fly from h (2MB, L2-resident).
__global__ __launch_bounds__(256) void k_front(
    const float* __restrict__ x,
    const float* __restrict__ w1, const float* __restrict__ b1,
    const float* __restrict__ w2, const float* __restrict__ b2,
    float* __restrict__ h,
    int* __restrict__ cnt,      // [N*CPAD], pre-zeroed
    float* __restrict__ bn_part, float* __restrict__ g,
    float* __restrict__ avg_log,
    const float* __restrict__ edge_emb,
    const float* __restrict__ enc_w, const float* __restrict__ enc_b,
    const float* __restrict__ pre_w, float* __restrict__ encm,
    const int* __restrict__ src, const int* __restrict__ dst,
    const int* __restrict__ attr, int* __restrict__ epk) {
  __shared__ float eo[2][4][10];
  int tid = threadIdx.x;
  int gid = blockIdx.x * 256 + tid;   // grid = 3125 blocks exactly -> gid < 800000

  // ---- scatter: count + take rank (payload stored after mlp1 compute) ----
  int ed = dst[gid];
  int es = src[gid];
  int ea = attr[gid];
  int rk = atomicAdd(&cnt[ed * CPAD], 1);

  // ---- housekeeping ----
  if (gid < 1280) bn_part[gid] = 0.f;          // [2][32][20]
  if (gid < G_GRAPHS * 10) g[gid] = 0.f;
  if (gid == 0) avg_log[0] = 0.f;
  { int z = gid - N_NODES; if (z >= 0 && z < 16) h[N_NODES * 10 + z] = 0.f; }  // zero row

  // ---- mlp1: 10 -> 5 -> 10 ----
  if (gid < N_NODES) {
    const float2* xp = (const float2*)(x + gid * 10);
    float xv[10];
#pragma unroll
    for (int k = 0; k < 5; k++) { float2 v = xp[k]; xv[2 * k] = v.x; xv[2 * k + 1] = v.y; }
    float hid[5];
#pragma unroll
    for (int j = 0; j < 5; j++) {
      float a = b1[j];
#pragma unroll
      for (int k = 0; k < 10; k++) a += xv[k] * w1[k * 5 + j];
      hid[j] = fmaxf(a, 0.f);
    }
#pragma unroll
    for (int f = 0; f < 10; f++) {
      float a = b2[f];
#pragma unroll
      for (int j = 0; j < 5; j++) a += hid[j] * w2[j * 10 + f];
      h[gid * 10 + f] = a;
    }
  }

  // ---- epk store: payload = src*40 + attr (40 % 8 == 0, attr in bits 0-1) ----
  if (rk < BSTRIDE) epk[ed * BSTRIDE + rk] = es * 40 + ea;

  // ---- enc/encm (block 0 only; all threads reach the barrier) ----
  if (blockIdx.x == 0) {
    for (int i = tid; i < 80; i += 256) {
      int l = i / 40; int a = (i / 10) % 4; int k = i % 10;
      float s = enc_b[l * 10 + k];
      for (int j = 0; j < 10; j++) s += edge_emb[a * 10 + j] * enc_w[(l * 10 + j) * 10 + k];
      eo[l][a][k] = s;
    }
  }
  __syncthreads();
  if (blockIdx.x == 0) {
    for (int i = tid; i < 400; i += 256) {
      int l = i / 200; int a = (i / 50) % 4; int t = (i / 10) % 5; int f = i % 10;
      float s = 0.f;
      for (int k = 0; k < 10; k++) s += eo[l][a][k] * pre_w[((l * 5 + t) * 30 + 20 + k) * 10 + f];
      encm[i] = s;
    }
  }
}

// ---- avg_log = sum_n log(deg_n + 1); ALSO pads epk slots [deg, deg+8) with the
// ---- sentinel so k_conv's 8-deep pipeline needs no bounds checks ----
__global__ void k_avg(const int* __restrict__ cnt, float* __restrict__ avg_log,
                      int* __restrict__ epk) {
  __shared__ float ws[4];
  int tid = threadIdx.x;
  float acc = 0.f;
  for (int n = blockIdx.x * 256 + tid; n < N_NODES; n += gridDim.x * 256) {
    int dg = cnt[n * CPAD];
    acc += __logf((float)dg + 1.f);
    int dd = dg < BSTRIDE ? dg : BSTRIDE;
    int end = dd + 8 < BSTRIDE ? dd + 8 : BSTRIDE;
    for (int j = dd; j < end; j++) epk[n * BSTRIDE + j] = SENPK;
  }
#pragma unroll
  for (int d = 32; d >= 1; d >>= 1) acc += __shfl_down(acc, d, 64);
  if ((tid & 63) == 0) ws[tid >> 6] = acc;
  __syncthreads();
  if (tid == 0) atomicAdd(avg_log, ws[0] + ws[1] + ws[2] + ws[3]);
}

// ---- fused PNA conv, one node per wave. Per edge: gather h[src] (40B, L2-hot,
// ---- lanes 0-9 one coalesced load), readlane-broadcast + 10 FMA on-the-fly dot
// ---- (same fp order as the old u precompute). Sentinel-padded epk -> no guards.
__global__ __launch_bounds__(256) void k_conv(
    const float* __restrict__ h,         // [N][10] + zero row
    const float* __restrict__ pre_w_l,   // [5][30][10]
    const float* __restrict__ pre_b_l,   // [5][10]
    const float* __restrict__ post_w_l,  // [5][130][2]
    const float* __restrict__ post_b_l,  // [5][2]
    const float* __restrict__ lin_w_l,   // [10][10]
    const float* __restrict__ lin_b_l,   // [10]
    const float* __restrict__ encm_l,    // [4][5][10]
    const int* __restrict__ cnt,         // [N*CPAD]
    const int* __restrict__ epk,         // [N][BSTRIDE], sentinel-padded
    const float* __restrict__ avg_log_p,
    float* __restrict__ o_buf,
    float* __restrict__ bn_part)         // [32][20]
{
  __shared__ float sW[1300];
  __shared__ float sLin[100];
  __shared__ float sLb[10];
  __shared__ float sPb[10];
  __shared__ float sP[4][100];
  __shared__ float sO[4][10];
  __shared__ float bnS[10], bnQ[10];

  int tid = threadIdx.x;
  int wid = RFL(tid >> 6);
  int lane = tid & 63;
  for (int i = tid; i < 1300; i += 256) sW[i] = post_w_l[i];
  for (int i = tid; i < 100; i += 256) sLin[i] = lin_w_l[i];
  if (tid < 10) {
    sLb[tid] = lin_b_l[tid];
    sPb[tid] = post_b_l[tid];
    bnS[tid] = 0.f; bnQ[tid] = 0.f;
  }
  __syncthreads();

  int f = lane % 10;
  int t = (lane < 50) ? (lane / 10) : 4;
  int c50 = t * 10 + f;
  const char* hb = (const char*)h;
  int f4 = f * 4;                      // per-lane byte offset into an h row
  float wdst[10], wsrc[10];
#pragma unroll
  for (int k = 0; k < 10; k++) wdst[k] = pre_w_l[(t * 30 + k) * 10 + f];
#pragma unroll
  for (int k = 0; k < 10; k++) wsrc[k] = pre_w_l[(t * 30 + 10 + k) * 10 + f];
  float em0 = encm_l[c50];
  float em1 = encm_l[50 + c50];
  float em2 = encm_l[100 + c50];
  float em3 = encm_l[150 + c50];
  float preb = pre_b_l[c50];
  float avg_log = avg_log_p[0] * (1.f / N_NODES);

  int n = blockIdx.x * 4 + wid;        // one node per wave; grid*4 == N_NODES
  float bnSv = 0.f, bnQv = 0.f;

#define PRE(HV, AS, IDX) { int sp_ = __builtin_amdgcn_readlane(pk, (IDX) & 63); \
    AS = sp_ & 3; \
    HV = *(const float*)(hb + (sp_ & ~7) + f4); }
#define PROC(HV, AS) { float us_ = 0.f; \
    _Pragma("unroll") \
    for (int k_ = 0; k_ < 10; k_++) us_ += RLF(HV, k_) * wsrc[k_]; \
    float m_ = ((AS & 2) ? ((AS & 1) ? bem3 : bem2) : ((AS & 1) ? bem1 : bem0)) + us_; \
    sum += m_; sq = fmaf(m_, m_, sq); mnv = fminf(mnv, m_); mxv = fmaxf(mxv, m_); }

  if (n < N_NODES) {
    int deg = RFL(cnt[n * CPAD]);      // scalar
    if (deg > BSTRIDE) deg = BSTRIDE;
    int pk = epk[n * BSTRIDE + lane];  // full row; slots >= deg+8 never readlane'd

    const float* hn = h + n * 10;
    float2 d0 = *(const float2*)hn;
    float2 d1 = *(const float2*)(hn + 2);
    float2 d2 = *(const float2*)(hn + 4);
    float2 d3 = *(const float2*)(hn + 6);
    float2 d4 = *(const float2*)(hn + 8);
    float xf = hn[f];

    float base = preb
      + d0.x * wdst[0] + d0.y * wdst[1] + d1.x * wdst[2] + d1.y * wdst[3]
      + d2.x * wdst[4] + d2.y * wdst[5] + d3.x * wdst[6] + d3.y * wdst[7]
      + d4.x * wdst[8] + d4.y * wdst[9];
    float bem0 = base + em0, bem1 = base + em1, bem2 = base + em2, bem3 = base + em3;

    float sum = 0.f, sq = 0.f, mnv = INFINITY, mxv = -INFINITY;
    {
      float u0, u1, u2, u3, u4, u5, u6, u7;
      int a0, a1, a2, a3, a4, a5, a6, a7;
      PRE(u0, a0, 0) PRE(u1, a1, 1) PRE(u2, a2, 2) PRE(u3, a3, 3)
      PRE(u4, a4, 4) PRE(u5, a5, 5) PRE(u6, a6, 6) PRE(u7, a7, 7)
      int full = deg & ~7;
      int jb = 0;
      for (; jb < full; jb += 8) {
        PROC(u0, a0) PRE(u0, a0, jb + 8)
        PROC(u1, a1) PRE(u1, a1, jb + 9)
        PROC(u2, a2) PRE(u2, a2, jb + 10)
        PROC(u3, a3) PRE(u3, a3, jb + 11)
        PROC(u4, a4) PRE(u4, a4, jb + 12)
        PROC(u5, a5) PRE(u5, a5, jb + 13)
        PROC(u6, a6) PRE(u6, a6, jb + 14)
        PROC(u7, a7) PRE(u7, a7, jb + 15)
      }
      if (jb + 0 < deg) PROC(u0, a0)
      if (jb + 1 < deg) PROC(u1, a1)
      if (jb + 2 < deg) PROC(u2, a2)
      if (jb + 3 < deg) PROC(u3, a3)
      if (jb + 4 < deg) PROC(u4, a4)
      if (jb + 5 < deg) PROC(u5, a5)
      if (jb + 6 < deg) PROC(u6, a6)
    }

    float degf = (float)deg;
    float d = fmaxf(degf, 1.f);
    float inv = 1.f / d;
    float mean = sum * inv;
    float var = sq * inv - mean * mean;
    float stdv = sqrtf(fmaxf(var, 0.f) + 1e-5f);
    if (deg == 0) { mnv = 0.f; mxv = 0.f; }
    float log_d = logf(d + 1.f);
    float amp = log_d / avg_log;
    float att = avg_log / log_d;

    float vv[13];
    vv[0] = xf;
    vv[1] = mean;       vv[2] = mnv;        vv[3] = mxv;        vv[4] = stdv;
    vv[5] = mean * amp; vv[6] = mnv * amp;  vv[7] = mxv * amp;  vv[8] = stdv * amp;
    vv[9] = mean * att; vv[10] = mnv * att; vv[11] = mxv * att; vv[12] = stdv * att;
    float p0 = 0.f, p1 = 0.f;
#pragma unroll
    for (int j = 0; j < 13; j++) {
      const float2 w = *(const float2*)&sW[t * 260 + (f + 10 * j) * 2];
      p0 += vv[j] * w.x; p1 += vv[j] * w.y;
    }
    if (lane < 50) *(float2*)&sP[wid][c50 * 2] = make_float2(p0, p1);
    WAVE_SYNC();
    if (lane < 10) {
      int tt = lane >> 1, c = lane & 1;
      float o = sPb[lane];
#pragma unroll
      for (int ff = 0; ff < 10; ff++) o += sP[wid][(tt * 10 + ff) * 2 + c];
      sO[wid][lane] = o;
    }
    WAVE_SYNC();
    if (lane < 10) {
      float r = sLb[lane];
#pragma unroll
      for (int j = 0; j < 10; j++) r += sO[wid][j] * sLin[j * 10 + lane];
      o_buf[n * 10 + lane] = r;
      bnSv = r; bnQv = r * r;
    }
  }
#undef PRE
#undef PROC

  if (lane < 10) {
    atomicAdd(&bnS[lane], bnSv);
    atomicAdd(&bnQ[lane], bnQv);
  }
  __syncthreads();
  if (tid < 20) {
    float v = (tid < 10) ? bnS[tid] : bnQ[tid - 10];
    atomicAdd(&bn_part[(blockIdx.x & 31) * 20 + tid], v);
  }
}

// ---- BN (from 32 partials) + relu (+ pool on last layer). 25 nodes/block ----
__global__ __launch_bounds__(256) void k_bnpool(
    const float* __restrict__ o_buf,
    const float* __restrict__ bn_part,  // [32][20]
    const float* __restrict__ gamma, const float* __restrict__ beta,
    float* __restrict__ h,              // [N][10]
    const int* __restrict__ batch, float* __restrict__ g,
    int do_pool) {
  __shared__ float sS[20];
  __shared__ float sMu[10], sInv[10];
  __shared__ float pool[8][10];
  __shared__ int g0s;
  int tid = threadIdx.x;
  int n0 = blockIdx.x * 25;
  if (tid < 20) {
    float s = 0.f;
    for (int j = 0; j < 32; j++) s += bn_part[j * 20 + tid];
    sS[tid] = s;
  }
  if (tid < 80) pool[tid / 10][tid % 10] = 0.f;
  if (tid == 0) g0s = batch[n0];
  __syncthreads();
  if (tid < 10) {
    float mu = sS[tid] * (1.f / N_NODES);
    float var = sS[10 + tid] * (1.f / N_NODES) - mu * mu;
    sMu[tid] = mu;
    sInv[tid] = 1.f / sqrtf(fmaxf(var, 0.f) + 1e-5f);
  }
  __syncthreads();
  if (tid < 250) {
    int dn = tid / 10, f = tid % 10;
    int n = n0 + dn;
    int i = n * 10 + f;
    float o = (o_buf[i] - sMu[f]) * sInv[f] * gamma[f] + beta[f];
    float r = fmaxf(o, 0.f);
    h[i] = r;
    if (do_pool) {
      int dg = batch[n] - g0s;
      if (dg < 8) atomicAdd(&pool[dg][f], r);
      else atomicAdd(&g[(g0s + dg) * 10 + f], r);
    }
  }
  if (do_pool) {
    __syncthreads();
    if (tid < 80) {
      float v = pool[tid / 10][tid % 10];
      if (v != 0.f) atomicAdd(&g[(g0s + tid / 10) * 10 + tid % 10], v);
    }
  }
}

// ---------------- mlp2 ----------------
__global__ void k_mlp2(const float* __restrict__ g,
                       const float* __restrict__ w1, const float* __restrict__ b1,
                       const float* __restrict__ w2, const float* __restrict__ b2,
                       float* __restrict__ out) {
  int b = threadIdx.x;
  if (b >= G_GRAPHS) return;
  float gv[10];
#pragma unroll
  for (int k = 0; k < 10; k++) gv[k] = g[b * 10 + k];
  float acc = b2[0];
#pragma unroll
  for (int j = 0; j < 5; j++) {
    float a = b1[j];
#pragma unroll
    for (int k = 0; k < 10; k++) a += gv[k] * w1[k * 5 + j];
    acc += fmaxf(a, 0.f) * w2[j];
  }
  out[b] = acc;
}

extern "C" void kernel_launch(void* const* d_in, const int* in_sizes, int n_in,
                              void* d_out, int out_size, void* d_ws, size_t ws_size,
                              hipStream_t stream) {
  const float* x        = (const float*)d_in[0];
  const float* edge_emb = (const float*)d_in[1];
  const float* m1w1 = (const float*)d_in[2];
  const float* m1b1 = (const float*)d_in[3];
  const float* m1w2 = (const float*)d_in[4];
  const float* m1b2 = (const float*)d_in[5];
  const float* enc_w = (const float*)d_in[6];
  const float* enc_b = (const float*)d_in[7];
  const float* pre_w = (const float*)d_in[8];
  const float* pre_b = (const float*)d_in[9];
  const float* post_w = (const float*)d_in[10];
  const float* post_b = (const float*)d_in[11];
  const float* lin_w = (const float*)d_in[12];
  const float* lin_b = (const float*)d_in[13];
  const float* bn_g = (const float*)d_in[14];
  const float* bn_b = (const float*)d_in[15];
  const float* m2w1 = (const float*)d_in[16];
  const float* m2b1 = (const float*)d_in[17];
  const float* m2w2 = (const float*)d_in[18];
  const float* m2b2 = (const float*)d_in[19];
  const int* edge_index = (const int*)d_in[20];
  const int* edge_attr  = (const int*)d_in[21];
  const int* batch      = (const int*)d_in[22];
  const int* src  = edge_index;
  const int* dstp = edge_index + N_EDGES;

  char* ws = (char*)d_ws;
  size_t off = 0;
  auto alloc = [&](size_t bytes) {
    void* p = ws + off;
    off += (bytes + 255) & ~(size_t)255;
    return p;
  };
  float*     h       = (float*)alloc((N_NODES * 10 + 16) * sizeof(float));
  float*     o_buf   = (float*)alloc(N_NODES * 10 * sizeof(float));
  int*       cnt     = (int*)alloc((size_t)N_NODES * CPAD * sizeof(int));
  int*       epk     = (int*)alloc((size_t)N_NODES * BSTRIDE * sizeof(int));
  float*     encm    = (float*)alloc(400 * sizeof(float));
  float*     avg_log = (float*)alloc(16);
  float*     bn_part = (float*)alloc(2 * 32 * 20 * sizeof(float));
  float*     g       = (float*)alloc(G_GRAPHS * 10 * sizeof(float));

  k_zero<<<(N_NODES + 255) / 256, 256, 0, stream>>>(cnt);

  k_front<<<N_EDGES / 256, 256, 0, stream>>>(x, m1w1, m1b1, m1w2, m1b2, h,
                                             cnt, bn_part, g, avg_log,
                                             edge_emb, enc_w, enc_b, pre_w, encm,
                                             src, dstp, edge_attr, epk);
  k_avg<<<64, 256, 0, stream>>>(cnt, avg_log, epk);

  for (int l = 0; l < 2; l++) {
    k_conv<<<N_NODES / 4, 256, 0, stream>>>(
        h, pre_w + l * 1500, pre_b + l * 50, post_w + l * 1300, post_b + l * 10,
        lin_w + l * 100, lin_b + l * 10, encm + l * 200,
        cnt, epk, avg_log, o_buf, bn_part + l * 640);
    k_bnpool<<<N_NODES / 25, 256, 0, stream>>>(
        o_buf, bn_part + l * 640, bn_g + l * 10, bn_b + l * 10, h, batch, g,
        l == 1);
  }
  k_mlp2<<<1, 64, 0, stream>>>(g, m2w1, m2b1, m2w2, m2b2, (float*)d_out);
}

// Round 6
// 270.074 us; speedup vs baseline: 1.2910x; 1.2910x over previous
//
#include <hip/hip_runtime.h>
#include <math.h>

#define N_NODES 50000
#define N_EDGES 800000
#define G_GRAPHS 64
#define BSTRIDE 64    // epk bucket stride per node (max degree; Poisson(16) tail ~1e-13)
#define CPAD 16       // cnt padded: one counter per 64B line
#define SENPK (N_NODES * 200)   // sentinel payload: byte offset of zero u row, attr=0

#define WAVE_SYNC() asm volatile("s_waitcnt lgkmcnt(0)" ::: "memory")
#define RFL(v) __builtin_amdgcn_readfirstlane(v)

// ---- zero the used cnt slots (graph-capture-safe memset) ----
__global__ void k_zero(int* __restrict__ cnt) {
  int n = blockIdx.x * 256 + threadIdx.x;
  if (n < N_NODES) cnt[n * CPAD] = 0;
}

// ---- fused front: edge scatter + mlp1 + u(layer0) + enc/encm setup ----
__global__ __launch_bounds__(256) void k_front(
    const float* __restrict__ x,
    const float* __restrict__ w1, const float* __restrict__ b1,
    const float* __restrict__ w2, const float* __restrict__ b2,
    float* __restrict__ h,
    int* __restrict__ cnt,      // [N*CPAD], pre-zeroed
    float* __restrict__ bn_part, float* __restrict__ g,
    float* __restrict__ avg_log,
    const float* __restrict__ edge_emb,
    const float* __restrict__ enc_w, const float* __restrict__ enc_b,
    const float* __restrict__ pre_w, float* __restrict__ encm,
    float* __restrict__ u,
    const int* __restrict__ src, const int* __restrict__ dst,
    const int* __restrict__ attr, int* __restrict__ epk) {
  __shared__ float eo[2][4][10];
  __shared__ float sw[500];   // layer-0 W_src: [t][k][f]
  int tid = threadIdx.x;
  int gid = blockIdx.x * 256 + tid;   // grid = 3125 blocks exactly -> gid < 800000

  // ---- scatter: count + take rank ----
  int ed = dst[gid];
  int es = src[gid];
  int ea = attr[gid];
  int rk = atomicAdd(&cnt[ed * CPAD], 1);

  // ---- housekeeping ----
  if (gid < 1280) bn_part[gid] = 0.f;          // [2][32][20]
  if (gid < G_GRAPHS * 10) g[gid] = 0.f;
  if (gid == 0) avg_log[0] = 0.f;
  { int z = gid - N_NODES; if (z >= 0 && z < 64) u[N_NODES * 50 + z] = 0.f; }  // zero u row

  // ---- mlp1: 10 -> 5 -> 10 ----
  bool act = gid < N_NODES;
  float hr[10];
  if (act) {
    const float2* xp = (const float2*)(x + gid * 10);
    float xv[10];
#pragma unroll
    for (int k = 0; k < 5; k++) { float2 v = xp[k]; xv[2 * k] = v.x; xv[2 * k + 1] = v.y; }
    float hid[5];
#pragma unroll
    for (int j = 0; j < 5; j++) {
      float a = b1[j];
#pragma unroll
      for (int k = 0; k < 10; k++) a += xv[k] * w1[k * 5 + j];
      hid[j] = fmaxf(a, 0.f);
    }
#pragma unroll
    for (int f = 0; f < 10; f++) {
      float a = b2[f];
#pragma unroll
      for (int j = 0; j < 5; j++) a += hid[j] * w2[j * 10 + f];
      hr[f] = a;
      h[gid * 10 + f] = a;
    }
  }

  // ---- stage layer-0 W_src ----
  for (int j = tid; j < 500; j += 256) {
    int t = j / 100, k = (j / 10) % 10, f = j % 10;
    sw[j] = pre_w[(t * 30 + 10 + k) * 10 + f];
  }

  // ---- epk store: payload = src*200 + attr (200 % 8 == 0, attr in bits 0-1) ----
  if (rk < BSTRIDE) epk[ed * BSTRIDE + rk] = es * 200 + ea;

  // ---- enc/encm (block 0 only; barrier is block-uniform) ----
  if (blockIdx.x == 0) {
    for (int i = tid; i < 80; i += 256) {
      int l = i / 40; int a = (i / 10) % 4; int k = i % 10;
      float s = enc_b[l * 10 + k];
      for (int j = 0; j < 10; j++) s += edge_emb[a * 10 + j] * enc_w[(l * 10 + j) * 10 + k];
      eo[l][a][k] = s;
    }
  }
  __syncthreads();
  if (blockIdx.x == 0) {
    for (int i = tid; i < 400; i += 256) {
      int l = i / 200; int a = (i / 50) % 4; int t = (i / 10) % 5; int f = i % 10;
      float s = 0.f;
      for (int k = 0; k < 10; k++) s += eo[l][a][k] * pre_w[((l * 5 + t) * 30 + 20 + k) * 10 + f];
      encm[i] = s;
    }
  }

  // ---- u(layer0): same FMA order as the original (absmax-preserving) ----
  if (act) {
    float2* up = (float2*)(u + gid * 50);
#pragma unroll
    for (int c0 = 0; c0 < 25; c0++) {
      int ca = 2 * c0, cb = 2 * c0 + 1;
      int ta = ca / 10, fa = ca % 10, tb = cb / 10, fb = cb % 10;
      float a = 0.f, b = 0.f;
#pragma unroll
      for (int k = 0; k < 10; k++) {
        a += hr[k] * sw[ta * 100 + fa + k * 10];
        b += hr[k] * sw[tb * 100 + fb + k * 10];
      }
      up[c0] = make_float2(a, b);
    }
  }
}

// ---- avg_log + sentinel-pad epk slots [deg, deg+8) ----
__global__ void k_avg(const int* __restrict__ cnt, float* __restrict__ avg_log,
                      int* __restrict__ epk) {
  __shared__ float ws[4];
  int tid = threadIdx.x;
  float acc = 0.f;
  for (int n = blockIdx.x * 256 + tid; n < N_NODES; n += gridDim.x * 256) {
    int dg = cnt[n * CPAD];
    acc += __logf((float)dg + 1.f);
    int dd = dg < BSTRIDE ? dg : BSTRIDE;
    int end = dd + 8 < BSTRIDE ? dd + 8 : BSTRIDE;
    for (int j = dd; j < end; j++) epk[n * BSTRIDE + j] = SENPK;
  }
#pragma unroll
  for (int d = 32; d >= 1; d >>= 1) acc += __shfl_down(acc, d, 64);
  if ((tid & 63) == 0) ws[tid >> 6] = acc;
  __syncthreads();
  if (tid == 0) atomicAdd(avg_log, ws[0] + ws[1] + ws[2] + ws[3]);
}

// ---- fused PNA conv: TWO nodes per wave, interleaved 4-deep pipelines
// ---- (8 independent u-gathers in flight per wave; round-3 was 1 node/8-deep
// ---- but latency-bound at 55% VALU busy). u-table gathers are L3-hit.
__global__ __launch_bounds__(256) void k_conv(
    const float* __restrict__ h,         // [N][10]
    const float* __restrict__ u,         // [N][50] + zero row
    const float* __restrict__ pre_w_l,   // [5][30][10]
    const float* __restrict__ pre_b_l,   // [5][10]
    const float* __restrict__ post_w_l,  // [5][130][2]
    const float* __restrict__ post_b_l,  // [5][2]
    const float* __restrict__ lin_w_l,   // [10][10]
    const float* __restrict__ lin_b_l,   // [10]
    const float* __restrict__ encm_l,    // [4][5][10]
    const int* __restrict__ cnt,         // [N*CPAD]
    const int* __restrict__ epk,         // [N][BSTRIDE], sentinel-padded
    const float* __restrict__ avg_log_p,
    float* __restrict__ o_buf,
    float* __restrict__ bn_part)         // [32][20]
{
  __shared__ float sW[1300];
  __shared__ float sLin[100];
  __shared__ float sLb[10];
  __shared__ float sPb[10];
  __shared__ float sP[4][100];
  __shared__ float sO[4][10];
  __shared__ float bnS[10], bnQ[10];

  int tid = threadIdx.x;
  int wid = RFL(tid >> 6);
  int lane = tid & 63;
  for (int i = tid; i < 1300; i += 256) sW[i] = post_w_l[i];
  for (int i = tid; i < 100; i += 256) sLin[i] = lin_w_l[i];
  if (tid < 10) {
    sLb[tid] = lin_b_l[tid];
    sPb[tid] = post_b_l[tid];
    bnS[tid] = 0.f; bnQ[tid] = 0.f;
  }
  __syncthreads();

  int f = lane % 10;
  int t = (lane < 50) ? (lane / 10) : 4;
  int c50 = t * 10 + f;
  const char* ub = (const char*)u;
  int c50_4 = c50 * 4;
  float wdst[10];
#pragma unroll
  for (int k = 0; k < 10; k++) wdst[k] = pre_w_l[(t * 30 + k) * 10 + f];
  float em0 = encm_l[c50];
  float em1 = encm_l[50 + c50];
  float em2 = encm_l[100 + c50];
  float em3 = encm_l[150 + c50];
  float preb = pre_b_l[c50];
  float avg_log = avg_log_p[0] * (1.f / N_NODES);

  int nA = (blockIdx.x * 4 + wid) * 2;   // grid*4*2 == N_NODES exactly
  int nB = nA + 1;
  float bnSv = 0.f, bnQv = 0.f;

  int degA = RFL(cnt[nA * CPAD]);
  int degB = RFL(cnt[nB * CPAD]);
  if (degA > BSTRIDE) degA = BSTRIDE;
  if (degB > BSTRIDE) degB = BSTRIDE;
  int pkA = epk[nA * BSTRIDE + lane];
  int pkB = epk[nB * BSTRIDE + lane];

  // h rows for both nodes (adjacent, 80B)
  const float* hnA = h + nA * 10;
  const float* hnB = h + nB * 10;
  float2 a0_ = *(const float2*)hnA, a1_ = *(const float2*)(hnA + 2),
         a2_ = *(const float2*)(hnA + 4), a3_ = *(const float2*)(hnA + 6),
         a4_ = *(const float2*)(hnA + 8);
  float2 b0_ = *(const float2*)hnB, b1_ = *(const float2*)(hnB + 2),
         b2_ = *(const float2*)(hnB + 4), b3_ = *(const float2*)(hnB + 6),
         b4_ = *(const float2*)(hnB + 8);
  float xfA = hnA[f], xfB = hnB[f];

  float baseA = preb
    + a0_.x * wdst[0] + a0_.y * wdst[1] + a1_.x * wdst[2] + a1_.y * wdst[3]
    + a2_.x * wdst[4] + a2_.y * wdst[5] + a3_.x * wdst[6] + a3_.y * wdst[7]
    + a4_.x * wdst[8] + a4_.y * wdst[9];
  float baseB = preb
    + b0_.x * wdst[0] + b0_.y * wdst[1] + b1_.x * wdst[2] + b1_.y * wdst[3]
    + b2_.x * wdst[4] + b2_.y * wdst[5] + b3_.x * wdst[6] + b3_.y * wdst[7]
    + b4_.x * wdst[8] + b4_.y * wdst[9];
  float bemA0 = baseA + em0, bemA1 = baseA + em1, bemA2 = baseA + em2, bemA3 = baseA + em3;
  float bemB0 = baseB + em0, bemB1 = baseB + em1, bemB2 = baseB + em2, bemB3 = baseB + em3;

  float sumA = 0.f, sqA = 0.f, mnA = INFINITY, mxA = -INFINITY;
  float sumB = 0.f, sqB = 0.f, mnB = INFINITY, mxB = -INFINITY;

#define PREA(S, IDX) { int sp_ = __builtin_amdgcn_readlane(pkA, (IDX) & 63); \
    aA##S = sp_ & 3; uA##S = *(const float*)(ub + (sp_ & ~7) + c50_4); }
#define PREB(S, IDX) { int sp_ = __builtin_amdgcn_readlane(pkB, (IDX) & 63); \
    aB##S = sp_ & 3; uB##S = *(const float*)(ub + (sp_ & ~7) + c50_4); }
#define PROCA(S) { float m_ = ((aA##S & 2) ? ((aA##S & 1) ? bemA3 : bemA2) : ((aA##S & 1) ? bemA1 : bemA0)) + uA##S; \
    sumA += m_; sqA = fmaf(m_, m_, sqA); mnA = fminf(mnA, m_); mxA = fmaxf(mxA, m_); }
#define PROCB(S) { float m_ = ((aB##S & 2) ? ((aB##S & 1) ? bemB3 : bemB2) : ((aB##S & 1) ? bemB1 : bemB0)) + uB##S; \
    sumB += m_; sqB = fmaf(m_, m_, sqB); mnB = fminf(mnB, m_); mxB = fmaxf(mxB, m_); }

  {
    float uA0, uA1, uA2, uA3, uB0, uB1, uB2, uB3;
    int aA0, aA1, aA2, aA3, aB0, aB1, aB2, aB3;
    PREA(0, 0) PREB(0, 0) PREA(1, 1) PREB(1, 1)
    PREA(2, 2) PREB(2, 2) PREA(3, 3) PREB(3, 3)
    int jmA = degA & ~3, jmB = degB & ~3;
    int mm = jmA < jmB ? jmA : jmB;
    int j = 0;
    for (; j < mm; j += 4) {
      PROCA(0) PREA(0, j + 4)
      PROCB(0) PREB(0, j + 4)
      PROCA(1) PREA(1, j + 5)
      PROCB(1) PREB(1, j + 5)
      PROCA(2) PREA(2, j + 6)
      PROCB(2) PREB(2, j + 6)
      PROCA(3) PREA(3, j + 7)
      PROCB(3) PREB(3, j + 7)
    }
    int jA = j, jB = j;
    for (; jA < jmA; jA += 4) {
      PROCA(0) PREA(0, jA + 4)
      PROCA(1) PREA(1, jA + 5)
      PROCA(2) PREA(2, jA + 6)
      PROCA(3) PREA(3, jA + 7)
    }
    for (; jB < jmB; jB += 4) {
      PROCB(0) PREB(0, jB + 4)
      PROCB(1) PREB(1, jB + 5)
      PROCB(2) PREB(2, jB + 6)
      PROCB(3) PREB(3, jB + 7)
    }
    if (jA + 0 < degA) PROCA(0)
    if (jA + 1 < degA) PROCA(1)
    if (jA + 2 < degA) PROCA(2)
    if (jB + 0 < degB) PROCB(0)
    if (jB + 1 < degB) PROCB(1)
    if (jB + 2 < degB) PROCB(2)
  }
#undef PREA
#undef PREB
#undef PROCA
#undef PROCB

  // ---- epilogue per node (sequential through per-wave LDS buffers) ----
#pragma unroll
  for (int sel = 0; sel < 2; sel++) {
    int n = sel ? nB : nA;
    int deg = sel ? degB : degA;
    float sum = sel ? sumB : sumA;
    float sq = sel ? sqB : sqA;
    float mnv = sel ? mnB : mnA;
    float mxv = sel ? mxB : mxA;
    float xf = sel ? xfB : xfA;

    float degf = (float)deg;
    float d = fmaxf(degf, 1.f);
    float inv = 1.f / d;
    float mean = sum * inv;
    float var = sq * inv - mean * mean;
    float stdv = sqrtf(fmaxf(var, 0.f) + 1e-5f);
    if (deg == 0) { mnv = 0.f; mxv = 0.f; }
    float log_d = logf(d + 1.f);
    float amp = log_d / avg_log;
    float att = avg_log / log_d;

    float vv[13];
    vv[0] = xf;
    vv[1] = mean;       vv[2] = mnv;        vv[3] = mxv;        vv[4] = stdv;
    vv[5] = mean * amp; vv[6] = mnv * amp;  vv[7] = mxv * amp;  vv[8] = stdv * amp;
    vv[9] = mean * att; vv[10] = mnv * att; vv[11] = mxv * att; vv[12] = stdv * att;
    float p0 = 0.f, p1 = 0.f;
#pragma unroll
    for (int j = 0; j < 13; j++) {
      const float2 w = *(const float2*)&sW[t * 260 + (f + 10 * j) * 2];
      p0 += vv[j] * w.x; p1 += vv[j] * w.y;
    }
    if (lane < 50) *(float2*)&sP[wid][c50 * 2] = make_float2(p0, p1);
    WAVE_SYNC();
    if (lane < 10) {
      int tt = lane >> 1, c = lane & 1;
      float o = sPb[lane];
#pragma unroll
      for (int ff = 0; ff < 10; ff++) o += sP[wid][(tt * 10 + ff) * 2 + c];
      sO[wid][lane] = o;
    }
    WAVE_SYNC();
    if (lane < 10) {
      float r = sLb[lane];
#pragma unroll
      for (int j = 0; j < 10; j++) r += sO[wid][j] * sLin[j * 10 + lane];
      o_buf[n * 10 + lane] = r;
      bnSv += r; bnQv += r * r;
    }
    WAVE_SYNC();
  }

  if (lane < 10) {
    atomicAdd(&bnS[lane], bnSv);
    atomicAdd(&bnQ[lane], bnQv);
  }
  __syncthreads();
  if (tid < 20) {
    float v = (tid < 10) ? bnS[tid] : bnQ[tid - 10];
    atomicAdd(&bn_part[(blockIdx.x & 31) * 20 + tid], v);
  }
}

// ---- BN (from 32 partials) + relu + fused u(next layer) OR pool. 25 nodes/block ----
__global__ __launch_bounds__(256) void k_bnpool(
    const float* __restrict__ o_buf,
    const float* __restrict__ bn_part,  // [32][20]
    const float* __restrict__ gamma, const float* __restrict__ beta,
    float* __restrict__ h,              // [N][10]
    const int* __restrict__ batch, float* __restrict__ g,
    const float* __restrict__ pre_w_next, float* __restrict__ u,
    int do_u, int do_pool) {
  __shared__ float sS[20];
  __shared__ float sMu[10], sInv[10];
  __shared__ float pool[8][10];
  __shared__ float hrow[25][10];
  __shared__ float sw[500];
  __shared__ int g0s;
  int tid = threadIdx.x;
  int n0 = blockIdx.x * 25;
  if (do_u) {
    for (int j = tid; j < 500; j += 256) {
      int t = j / 100, k = (j / 10) % 10, f = j % 10;
      sw[j] = pre_w_next[(t * 30 + 10 + k) * 10 + f];
    }
  }
  if (tid < 20) {
    float s = 0.f;
    for (int j = 0; j < 32; j++) s += bn_part[j * 20 + tid];
    sS[tid] = s;
  }
  if (tid < 80) pool[tid / 10][tid % 10] = 0.f;
  if (tid == 0) g0s = batch[n0];
  __syncthreads();
  if (tid < 10) {
    float mu = sS[tid] * (1.f / N_NODES);
    float var = sS[10 + tid] * (1.f / N_NODES) - mu * mu;
    sMu[tid] = mu;
    sInv[tid] = 1.f / sqrtf(fmaxf(var, 0.f) + 1e-5f);
  }
  __syncthreads();
  if (tid < 250) {
    int dn = tid / 10, f = tid % 10;
    int n = n0 + dn;
    int i = n * 10 + f;
    float o = (o_buf[i] - sMu[f]) * sInv[f] * gamma[f] + beta[f];
    float r = fmaxf(o, 0.f);
    h[i] = r;
    hrow[dn][f] = r;
    if (do_pool) {
      int dg = batch[n] - g0s;
      if (dg < 8) atomicAdd(&pool[dg][f], r);
      else atomicAdd(&g[(g0s + dg) * 10 + f], r);
    }
  }
  __syncthreads();
  if (do_u && tid < 250) {
#pragma unroll
    for (int it = 0; it < 5; it++) {
      int j = tid + it * 250;
      int node = j / 50, c = j % 50;
      int t = c / 10, f2 = c % 10;
      float acc = 0.f;
#pragma unroll
      for (int k = 0; k < 10; k++) acc += hrow[node][k] * sw[t * 100 + f2 + k * 10];
      u[n0 * 50 + j] = acc;
    }
  }
  if (do_pool) {
    __syncthreads();
    if (tid < 80) {
      float v = pool[tid / 10][tid % 10];
      if (v != 0.f) atomicAdd(&g[(g0s + tid / 10) * 10 + tid % 10], v);
    }
  }
}

// ---------------- mlp2 ----------------
__global__ void k_mlp2(const float* __restrict__ g,
                       const float* __restrict__ w1, const float* __restrict__ b1,
                       const float* __restrict__ w2, const float* __restrict__ b2,
                       float* __restrict__ out) {
  int b = threadIdx.x;
  if (b >= G_GRAPHS) return;
  float gv[10];
#pragma unroll
  for (int k = 0; k < 10; k++) gv[k] = g[b * 10 + k];
  float acc = b2[0];
#pragma unroll
  for (int j = 0; j < 5; j++) {
    float a = b1[j];
#pragma unroll
    for (int k = 0; k < 10; k++) a += gv[k] * w1[k * 5 + j];
    acc += fmaxf(a, 0.f) * w2[j];
  }
  out[b] = acc;
}

extern "C" void kernel_launch(void* const* d_in, const int* in_sizes, int n_in,
                              void* d_out, int out_size, void* d_ws, size_t ws_size,
                              hipStream_t stream) {
  const float* x        = (const float*)d_in[0];
  const float* edge_emb = (const float*)d_in[1];
  const float* m1w1 = (const float*)d_in[2];
  const float* m1b1 = (const float*)d_in[3];
  const float* m1w2 = (const float*)d_in[4];
  const float* m1b2 = (const float*)d_in[5];
  const float* enc_w = (const float*)d_in[6];
  const float* enc_b = (const float*)d_in[7];
  const float* pre_w = (const float*)d_in[8];
  const float* pre_b = (const float*)d_in[9];
  const float* post_w = (const float*)d_in[10];
  const float* post_b = (const float*)d_in[11];
  const float* lin_w = (const float*)d_in[12];
  const float* lin_b = (const float*)d_in[13];
  const float* bn_g = (const float*)d_in[14];
  const float* bn_b = (const float*)d_in[15];
  const float* m2w1 = (const float*)d_in[16];
  const float* m2b1 = (const float*)d_in[17];
  const float* m2w2 = (const float*)d_in[18];
  const float* m2b2 = (const float*)d_in[19];
  const int* edge_index = (const int*)d_in[20];
  const int* edge_attr  = (const int*)d_in[21];
  const int* batch      = (const int*)d_in[22];
  const int* src  = edge_index;
  const int* dstp = edge_index + N_EDGES;

  char* ws = (char*)d_ws;
  size_t off = 0;
  auto alloc = [&](size_t bytes) {
    void* p = ws + off;
    off += (bytes + 255) & ~(size_t)255;
    return p;
  };
  float*     h       = (float*)alloc(N_NODES * 10 * sizeof(float));
  float*     o_buf   = (float*)alloc(N_NODES * 10 * sizeof(float));
  float*     u       = (float*)alloc((size_t)(N_NODES * 50 + 64) * sizeof(float));
  int*       cnt     = (int*)alloc((size_t)N_NODES * CPAD * sizeof(int));
  int*       epk     = (int*)alloc((size_t)N_NODES * BSTRIDE * sizeof(int));
  float*     encm    = (float*)alloc(400 * sizeof(float));
  float*     avg_log = (float*)alloc(16);
  float*     bn_part = (float*)alloc(2 * 32 * 20 * sizeof(float));
  float*     g       = (float*)alloc(G_GRAPHS * 10 * sizeof(float));

  k_zero<<<(N_NODES + 255) / 256, 256, 0, stream>>>(cnt);

  k_front<<<N_EDGES / 256, 256, 0, stream>>>(x, m1w1, m1b1, m1w2, m1b2, h,
                                             cnt, bn_part, g, avg_log,
                                             edge_emb, enc_w, enc_b, pre_w, encm, u,
                                             src, dstp, edge_attr, epk);
  k_avg<<<64, 256, 0, stream>>>(cnt, avg_log, epk);

  for (int l = 0; l < 2; l++) {
    k_conv<<<N_NODES / 8, 256, 0, stream>>>(
        h, u, pre_w + l * 1500, pre_b + l * 50, post_w + l * 1300, post_b + l * 10,
        lin_w + l * 100, lin_b + l * 10, encm + l * 200,
        cnt, epk, avg_log, o_buf, bn_part + l * 640);
    k_bnpool<<<N_NODES / 25, 256, 0, stream>>>(
        o_buf, bn_part + l * 640, bn_g + l * 10, bn_b + l * 10, h, batch, g,
        pre_w + 1500, u, l == 0, l == 1);
  }
  k_mlp2<<<1, 64, 0, stream>>>(g, m2w1, m2b1, m2w2, m2b2, (float*)d_out);
}